// Round 1
// baseline (342.793 us; speedup 1.0000x reference)
//
#include <hip/hip_runtime.h>

// Sorted-segment product: out[i] = prod_{j: csr[j]==i} x[ptrs[j]], empty -> 0.
//
// R5: kill the latency serialization of R4's window-phased gather.
// R4 had 16 barrier-phases/superchunk with ~1 active gather per thread per
// phase (EPT=16 spread over 16 windows) -> 1-deep MLP, vmcnt(0)+barrier per
// phase. Counters: 29% HBM, 9% VALU, 0 bank conflicts => latency-bound.
//
// New gather: per-thread bitonic sort of the 16 ptrs (packed (ptr<<4)|k,
// static 80-CE network). Sorted quartiles make phases uniform and
// UNPREDICATED: phase p = exactly 4 independent loads, software-pipelined
// (issue quartile p+1, LDS-mirror quartile p -> partial vmcnt, barrier).
// 4 phases instead of 16, ~4-deep MLP per wave, no exposed load latency.
// Same approximate cross-block phase alignment (order statistics of sorted
// quantiles) preserves the L2 reuse that windowing bought.
// Product phase reads values from the gbuf mirror (conflict-free b32 reads).

#define EPT       16              // edges per thread
#define EPT_SHIFT 4
#define BLK       1024            // threads per block (16 waves)
#define MSC       (BLK * EPT)     // 16384 edges per superchunk
#define NBLK      512             // persistent blocks (2 per CU)
#define NPH       4               // gather phases (sorted quartiles)
#define MPL       (EPT / NPH)     // loads per phase = 4

// issue quartile p's 4 independent gathers into buf[0..3]
#define ISSUE(buf, p)                                                   \
    {                                                                   \
        _Pragma("unroll")                                               \
        for (int m = 0; m < MPL; ++m)                                   \
            buf[m] = x[key[(p) * MPL + m] >> EPT_SHIFT];                \
    }
// mirror quartile p's values to their original-k columns in LDS
#define WRITE(buf, p)                                                   \
    {                                                                   \
        _Pragma("unroll")                                               \
        for (int m = 0; m < MPL; ++m)                                   \
            gbuf[(key[(p) * MPL + m] & (EPT - 1)) * BLK + t] = buf[m];  \
    }

__global__ __launch_bounds__(BLK, 8) void prodseg_main(
    const float* __restrict__ x,
    const int*   __restrict__ ptrs,
    const int*   __restrict__ csr,
    float*       __restrict__ out,
    int E, int S, int F /* # full superchunks */)
{
    __shared__ float gbuf[MSC];   // column-major: edge (t,k) -> gbuf[k*BLK + t]
    const int t = threadIdx.x;
    const int ngen = (F + (int)gridDim.x - 1) / (int)gridDim.x;

    for (int gen = 0; gen < ngen; ++gen) {
        int sc = gen * (int)gridDim.x + (int)blockIdx.x;
        if (sc >= F) break;                    // block-uniform exit
        const int sbase = sc * MSC;
        const int gbase = sbase + t * EPT;

        // ---- stage my 16 ptrs, packed (ptr<<4)|k ----
        unsigned key[EPT];
        {
            const int4* p4 = reinterpret_cast<const int4*>(ptrs + gbase);
            #pragma unroll
            for (int i = 0; i < EPT / 4; ++i) {
                int4 v = p4[i];
                key[4*i+0] = ((unsigned)v.x << EPT_SHIFT) | (unsigned)(4*i+0);
                key[4*i+1] = ((unsigned)v.y << EPT_SHIFT) | (unsigned)(4*i+1);
                key[4*i+2] = ((unsigned)v.z << EPT_SHIFT) | (unsigned)(4*i+2);
                key[4*i+3] = ((unsigned)v.w << EPT_SHIFT) | (unsigned)(4*i+3);
            }
        }

        // ---- bitonic sort (static network, all indices compile-time) ----
        #pragma unroll
        for (int k = 2; k <= EPT; k <<= 1) {
            #pragma unroll
            for (int j = k >> 1; j > 0; j >>= 1) {
                #pragma unroll
                for (int i = 0; i < EPT; ++i) {
                    int l = i ^ j;
                    if (l > i) {
                        unsigned a = key[i], b = key[l];
                        bool up = (i & k) == 0;
                        bool sw = up ? (a > b) : (a < b);
                        key[i] = sw ? b : a;
                        key[l] = sw ? a : b;
                    }
                }
            }
        }

        // ---- pipelined sorted-quartile gather ----
        // issue(p+1) before write(p): write's vmcnt only covers loads issued
        // one full phase ago (already landed) -> no exposed latency.
        {
            float ga[MPL], gb[MPL];
            ISSUE(ga, 0);
            ISSUE(gb, 1); WRITE(ga, 0); __syncthreads();
            ISSUE(ga, 2); WRITE(gb, 1); __syncthreads();
            ISSUE(gb, 3); WRITE(ga, 2); __syncthreads();
            WRITE(gb, 3); __syncthreads();   // doubles as pre-product barrier
        }

        // ---- product phase (run ownership, exact) ----
        int prev = (gbase == 0) ? -1 : csr[gbase - 1];
        const int4* c4 = reinterpret_cast<const int4*>(csr + gbase);
        int cur = 0; bool own = false; float prod = 1.0f;
        #pragma unroll
        for (int i = 0; i < EPT / 4; ++i) {
            int4 c = c4[i];
            int sv[4] = {c.x, c.y, c.z, c.w};
            #pragma unroll
            for (int j = 0; j < 4; ++j) {
                const int k = 4 * i + j;
                int sg = sv[j];
                float gk = gbuf[k * BLK + t];   // own column, conflict-free
                if (k == 0) {
                    cur = sg; own = (sg != prev);
                    prod = own ? gk : 1.0f;
                    if (own)
                        for (int q = prev + 1; q < cur; ++q) out[q] = 0.0f;
                } else {
                    if (sg == cur) {
                        prod *= gk;            // harmless if !own (never stored)
                    } else {
                        if (own) out[cur] = prod;
                        for (int q = cur + 1; q < sg; ++q) out[q] = 0.0f;
                        cur = sg; own = true; prod = gk;
                    }
                }
            }
        }
        // final run: walk forward; in-superchunk values come from LDS
        if (own) {
            int idx = gbase + EPT;
            while (idx < E) {
                if (csr[idx] != cur) break;
                float v;
                int local = idx - sbase;
                if (local < MSC)
                    v = gbuf[(local & (EPT - 1)) * BLK + (local >> EPT_SHIFT)];
                else
                    v = x[ptrs[idx]];
                prod *= v; ++idx;
            }
            out[cur] = prod;
            if (idx == E)
                for (int q = cur + 1; q < S; ++q) out[q] = 0.0f;
        }
        __syncthreads();   // protect gbuf before next generation
    }
}

// Generic tail (E % MSC != 0) — R1-proven logic; not launched for E = 2^24.
#define TK 8
__global__ __launch_bounds__(256) void prodseg_tail(
    const float* __restrict__ x,
    const int*   __restrict__ ptrs,
    const int*   __restrict__ csr,
    float*       __restrict__ out,
    int E0, int E, int S)
{
    int t = blockIdx.x * blockDim.x + threadIdx.x;
    int base = E0 + t * TK;
    if (base >= E) return;
    int prev = (base == 0) ? -1 : csr[base - 1];
    int n = (base + TK <= E) ? TK : (E - base);

    int cur = 0; bool own = false; float prod = 1.0f;
    for (int k = 0; k < n; ++k) {
        int sg = csr[base + k];
        float gv = x[ptrs[base + k]];
        if (k == 0) {
            cur = sg; own = (sg != prev);
            prod = own ? gv : 1.0f;
            if (own) for (int q = prev + 1; q < cur; ++q) out[q] = 0.0f;
        } else if (sg == cur) {
            prod *= gv;
        } else {
            if (own) out[cur] = prod;
            for (int q = cur + 1; q < sg; ++q) out[q] = 0.0f;
            cur = sg; own = true; prod = gv;
        }
    }
    if (own) {
        int idx = base + n;
        while (idx < E && csr[idx] == cur) { prod *= x[ptrs[idx]]; ++idx; }
        out[cur] = prod;
        if (idx == E) for (int q = cur + 1; q < S; ++q) out[q] = 0.0f;
    }
}

extern "C" void kernel_launch(void* const* d_in, const int* in_sizes, int n_in,
                              void* d_out, int out_size, void* d_ws, size_t ws_size,
                              hipStream_t stream) {
    const float* x    = (const float*)d_in[0];
    const int*   ptrs = (const int*)d_in[1];
    const int*   csr  = (const int*)d_in[2];
    float*       out  = (float*)d_out;
    int E = in_sizes[1];
    int S = out_size;

    int F  = E / MSC;                                   // full superchunks
    int E0 = F * MSC;

    if (F > 0)
        prodseg_main<<<NBLK, BLK, 0, stream>>>(x, ptrs, csr, out, E, S, F);
    if (E0 < E) {
        int nt = (E - E0 + TK - 1) / TK;
        prodseg_tail<<<(nt + 255) / 256, 256, 0, stream>>>(x, ptrs, csr, out, E0, E, S);
    }
}

// Round 2
// 327.755 us; speedup vs baseline: 1.0459x; 1.0459x over previous
//
#include <hip/hip_runtime.h>

// Sorted-segment product: out[i] = prod_{j: csr[j]==i} x[ptrs[j]], empty -> 0.
//
// R6 = R4's issue pattern + R5's wait structure.
//   R4 (189us): exact 1MB-window predicated gather -> FETCH 382MB (near
//     compulsory), but __syncthreads() per window forces vmcnt(0) drain
//     (HIP compiler emits full waitcnt before s_barrier) -> 16 exposed
//     full-latency stalls per superchunk, 1-deep MLP. Latency-bound.
//   R5 (233us): pipelined sorted quartiles -> great MLP, but per-thread
//     order statistics are noisy: phase bands ~4-8MB > 4MiB per-XCD L2
//     -> FETCH 778MB, BW-bound on wasted traffic.
// Fix: keep the 16 predicated windows EXACTLY (locality), but
//   (a) raw __builtin_amdgcn_s_barrier() between windows — aligns phases
//       for L2 locality WITHOUT draining vmcnt (8-phase-GEMM mechanism);
//   (b) defer the LDS mirror to after the window loop — values accumulate
//       in g[16] registers, loads stay in flight (up to 16 outstanding),
//       ONE vmcnt drain per superchunk instead of 16.

#define EPT       16              // edges per thread (pt[16]+g[16] = 32 VGPRs)
#define EPT_SHIFT 4
#define BLK       1024            // threads per block (16 waves)
#define MSC       (BLK * EPT)     // 16384 edges per superchunk
#define NBLK      512             // persistent blocks (2 per CU)
#define WSHIFT    18              // window = 2^18 floats = 1 MB

__global__ __launch_bounds__(BLK, 8) void prodseg_main(
    const float* __restrict__ x,
    const int*   __restrict__ ptrs,
    const int*   __restrict__ csr,
    float*       __restrict__ out,
    int E, int S, int F /* # full superchunks */, int nwin)
{
    __shared__ float gbuf[MSC];   // column-major: edge (t,k) -> gbuf[k*BLK + t]
    const int t = threadIdx.x;
    const int ngen = (F + (int)gridDim.x - 1) / (int)gridDim.x;

    for (int gen = 0; gen < ngen; ++gen) {
        int sc = gen * (int)gridDim.x + (int)blockIdx.x;
        if (sc >= F) break;                    // block-uniform exit
        const int sbase = sc * MSC;
        const int gbase = sbase + t * EPT;

        // ---- stage my 16 ptrs into registers (vectorized, aligned) ----
        int pt[EPT];
        {
            const int4* p4 = reinterpret_cast<const int4*>(ptrs + gbase);
            #pragma unroll
            for (int i = 0; i < EPT / 4; ++i) {
                int4 v = p4[i];
                pt[4*i+0] = v.x; pt[4*i+1] = v.y;
                pt[4*i+2] = v.z; pt[4*i+3] = v.w;
            }
        }

        // ---- window-phased gather: issue only, never wait ----
        // Raw s_barrier keeps the block's waves window-aligned (L2 reuse)
        // but does NOT force a vmcnt drain; g[] isn't consumed until the
        // LDS mirror below, so up to 16 loads/thread stay in flight.
        float g[EPT];
        for (int w = 0; w < nwin; ++w) {
            #pragma unroll
            for (int k = 0; k < EPT; ++k)
                if ((pt[k] >> WSHIFT) == w) g[k] = x[pt[k]];
            __builtin_amdgcn_s_barrier();       // align, no drain
            __builtin_amdgcn_sched_barrier(0);  // pin: no cross-window motion
        }

        // ---- single drain: mirror to LDS for cross-thread run walks ----
        #pragma unroll
        for (int k = 0; k < EPT; ++k)
            gbuf[k * BLK + t] = g[k];
        __syncthreads();

        // ---- product phase (run ownership, exact) ----
        int prev = (gbase == 0) ? -1 : csr[gbase - 1];
        const int4* c4 = reinterpret_cast<const int4*>(csr + gbase);
        int cur = 0; bool own = false; float prod = 1.0f;
        #pragma unroll
        for (int i = 0; i < EPT / 4; ++i) {
            int4 c = c4[i];
            int sv[4] = {c.x, c.y, c.z, c.w};
            #pragma unroll
            for (int j = 0; j < 4; ++j) {
                const int k = 4 * i + j;
                int sg = sv[j];
                if (k == 0) {
                    cur = sg; own = (sg != prev);
                    prod = own ? g[0] : 1.0f;
                    if (own)
                        for (int q = prev + 1; q < cur; ++q) out[q] = 0.0f;
                } else {
                    if (sg == cur) {
                        prod *= g[k];          // harmless if !own (never stored)
                    } else {
                        if (own) out[cur] = prod;
                        for (int q = cur + 1; q < sg; ++q) out[q] = 0.0f;
                        cur = sg; own = true; prod = g[k];
                    }
                }
            }
        }
        // final run: walk forward; in-superchunk values come from LDS
        if (own) {
            int idx = gbase + EPT;
            while (idx < E) {
                if (csr[idx] != cur) break;
                float v;
                int local = idx - sbase;
                if (local < MSC)
                    v = gbuf[(local & (EPT - 1)) * BLK + (local >> EPT_SHIFT)];
                else
                    v = x[ptrs[idx]];
                prod *= v; ++idx;
            }
            out[cur] = prod;
            if (idx == E)
                for (int q = cur + 1; q < S; ++q) out[q] = 0.0f;
        }
        __syncthreads();   // protect gbuf before next generation
    }
}

// Generic tail (E % MSC != 0) — R1-proven logic; not launched for E = 2^24.
#define TK 8
__global__ __launch_bounds__(256) void prodseg_tail(
    const float* __restrict__ x,
    const int*   __restrict__ ptrs,
    const int*   __restrict__ csr,
    float*       __restrict__ out,
    int E0, int E, int S)
{
    int t = blockIdx.x * blockDim.x + threadIdx.x;
    int base = E0 + t * TK;
    if (base >= E) return;
    int prev = (base == 0) ? -1 : csr[base - 1];
    int n = (base + TK <= E) ? TK : (E - base);

    int cur = 0; bool own = false; float prod = 1.0f;
    for (int k = 0; k < n; ++k) {
        int sg = csr[base + k];
        float gv = x[ptrs[base + k]];
        if (k == 0) {
            cur = sg; own = (sg != prev);
            prod = own ? gv : 1.0f;
            if (own) for (int q = prev + 1; q < cur; ++q) out[q] = 0.0f;
        } else if (sg == cur) {
            prod *= gv;
        } else {
            if (own) out[cur] = prod;
            for (int q = cur + 1; q < sg; ++q) out[q] = 0.0f;
            cur = sg; own = true; prod = gv;
        }
    }
    if (own) {
        int idx = base + n;
        while (idx < E && csr[idx] == cur) { prod *= x[ptrs[idx]]; ++idx; }
        out[cur] = prod;
        if (idx == E) for (int q = cur + 1; q < S; ++q) out[q] = 0.0f;
    }
}

extern "C" void kernel_launch(void* const* d_in, const int* in_sizes, int n_in,
                              void* d_out, int out_size, void* d_ws, size_t ws_size,
                              hipStream_t stream) {
    const float* x    = (const float*)d_in[0];
    const int*   ptrs = (const int*)d_in[1];
    const int*   csr  = (const int*)d_in[2];
    float*       out  = (float*)d_out;
    int N = in_sizes[0];
    int E = in_sizes[1];
    int S = out_size;

    int F  = E / MSC;                                   // full superchunks
    int E0 = F * MSC;
    int nwin = (N + (1 << WSHIFT) - 1) >> WSHIFT;       // 16 for N = 2^22

    if (F > 0)
        prodseg_main<<<NBLK, BLK, 0, stream>>>(x, ptrs, csr, out, E, S, F, nwin);
    if (E0 < E) {
        int nt = (E - E0 + TK - 1) / TK;
        prodseg_tail<<<(nt + 255) / 256, 256, 0, stream>>>(x, ptrs, csr, out, E0, E, S);
    }
}